// Round 16
// baseline (588.141 us; speedup 1.0000x reference)
//
#include <hip/hip_runtime.h>
#include <hip/hip_fp16.h>
#include <math.h>

// Problem constants: tenIn [8,64,288,512] fp32, flow [8,2,H,W], metric [8,1,H,W].
constexpr int N  = 8;
constexpr int C  = 64;
constexpr int H  = 288;
constexpr int W  = 512;               // power of 2
constexpr int HW = H * W;             // 147456

// Output tiling (R13/R15-proven): 64x32 tiles. R covers max corner
// displacement for this data; escape path (folded into claim) handles
// anything larger exactly, so R is perf-only.
constexpr int TW = 64, TH = 32, R = 8;
constexpr int PW = TW + 2 * R;        // 80
constexpr int PH = TH + 2 * R;        // 48
constexpr int PS = PW * PH;           // 3840 (fits u16)
constexpr int TGX = W / TW;           // 8
constexpr int TGY = H / TH;           // 9
constexpr int TILES = N * TGX * TGY;  // 576
constexpr int NOUT = TH * TW;         // 2048 outputs per tile
constexpr int K = 12;                 // slots per output (zero-filled if unused)
constexpr int CCHB = 4;               // channels per chunk (4 x f16 = 8B entry)
constexpr int NCHUNK = C / CCHB;      // 16
constexpr int NSPLIT = 2;             // channel-halves across gather blocks
constexpr int CPB = NCHUNK / NSPLIT;  // 8 chunks per gather block
constexpr int OVFCAP = 256;           // per-tile overflow entries (slot > K)
constexpr int ESCCAP = 512;           // per-tile escape entries (|disp| > R)
constexpr int NTC = 512;              // claim threads
constexpr int NTG = 512;              // gather threads (8 waves/block)
constexpr int OPT = NOUT / NTG;       // 4 outputs per gather thread
constexpr int GGRID = TILES * NSPLIT; // 1152 = 8 XCDs * 144

// Claim dynamic LDS: cnt[NOUT] + meta[NOUT*K], all u32.
constexpr size_t CLAIM_LDS_WORDS = (size_t)NOUT * (K + 1);      // 26624
constexpr size_t CLAIM_LDS_BYTES = CLAIM_LDS_WORDS * 4;         // 106496

// Workspace layout (4-byte words). Total ~71 MB.
constexpr size_t WS_DEN  = 0;                                    // N*HW f32
constexpr size_t WS_META = WS_DEN  + (size_t)N * HW;             // TILES*NOUT*K (output-major)
constexpr size_t WS_OVFC = WS_META + (size_t)TILES * NOUT * K;   // TILES
constexpr size_t WS_OVFE = WS_OVFC + TILES;                      // TILES*OVFCAP*2
constexpr size_t WS_ESCC = WS_OVFE + (size_t)TILES * OVFCAP * 2; // TILES
constexpr size_t WS_ESCE = WS_ESCC + TILES;                      // TILES*ESCCAP*3

// Entry-index swizzle for 8B entries (bank pair = e mod 16): XOR low 4 bits
// with bits 4..7 -> bijective within each 16-block (PS % 16 == 0), spreads
// staging writes and random reads across banks. si PRE-swizzled at claim.
__device__ __forceinline__ int swz(int si) { return si ^ ((si >> 4) & 15); }

__device__ __forceinline__ unsigned packh2(float a, float b) {
    __half2 h = __floats2half2_rn(a, b);
    return *reinterpret_cast<unsigned*>(&h);
}
__device__ __forceinline__ float2 unpackh2(unsigned u) {
    __half2 h = *reinterpret_cast<__half2*>(&u);
    return __half22float2(h);
}

// ---------------------------------------------------------------------------
// Kernel 1: per-tile claim, LDS-buffered meta, ESCAPE FOLDED IN (unchanged
// from R15). Slot claims into LDS meta [o][K]; den from LDS; coalesced uint4
// flush. Core pixels append out-of-halo corners to the target tile's escape
// list (device atomics; empty for this data); gather adds them to den.
// ---------------------------------------------------------------------------
__global__ __launch_bounds__(NTC) void claim_kernel(
    const float* __restrict__ flow, const float* __restrict__ metric,
    unsigned* __restrict__ meta,
    unsigned* __restrict__ ovfc, unsigned* __restrict__ ovfe,
    unsigned* __restrict__ escc, unsigned* __restrict__ esce,
    float* __restrict__ den)
{
    extern __shared__ unsigned smem[];
    unsigned* cnt = smem;              // NOUT
    unsigned* ml  = smem + NOUT;       // NOUT*K, output-major [o][K]

    for (int i = threadIdx.x; i < NOUT; i += NTC) cnt[i] = 0;
    for (int i = threadIdx.x; i < NOUT * K; i += NTC) ml[i] = 0u;
    __syncthreads();

    const int t  = blockIdx.x;
    const int n  = t / (TGX * TGY);
    const int r  = t % (TGX * TGY);
    const int Y0 = (r / TGX) * TH;
    const int X0 = (r % TGX) * TW;

    const float* fxp = flow + ((size_t)n * 2) * HW;
    const float* fyp = fxp + HW;
    const float* mp  = metric + (size_t)n * HW;
    unsigned* mt = meta + (size_t)t * NOUT * K;

    for (int si = threadIdx.x; si < PS; si += NTC) {
        int ys = Y0 - R + si / PW;
        int xs = X0 - R + si % PW;
        if ((unsigned)ys >= (unsigned)H || (unsigned)xs >= (unsigned)W) continue;
        int p = ys * W + xs;
        float fx = fxp[p] + (float)xs;
        float fy = fyp[p] + (float)ys;
        if (!(isfinite(fx) && isfinite(fy))) continue;
        float x0f = floorf(fx), y0f = floorf(fy);
        int ix0 = (int)x0f, iy0 = (int)y0f;
        int tx = ix0 - X0;
        int ty = iy0 - Y0;
        float wx1 = fx - x0f, wx0 = x0f + 1.0f - fx;
        float wy1 = fy - y0f, wy0 = y0f + 1.0f - fy;
        float wm  = __expf(mp[p]);
        int sis = swz(si);                  // pre-swizzled LDS entry index

        #define CLAIM(TYv, TXv, Wv)                                           \
            if ((unsigned)(TYv) < (unsigned)TH &&                             \
                (unsigned)(TXv) < (unsigned)TW) {                             \
                float w_ = (Wv) * wm;                                         \
                int   o_ = (TYv) * TW + (TXv);                                \
                unsigned slot = atomicAdd(&cnt[o_], 1u);                      \
                if (slot < (unsigned)K) {                                     \
                    ml[o_ * K + (int)slot] =                                  \
                        ((unsigned)__half_as_ushort(__float2half(w_)) << 16)  \
                        | (unsigned)sis;                                      \
                } else {                                                      \
                    unsigned p2 = atomicAdd(&ovfc[t], 1u);                    \
                    if (p2 < (unsigned)OVFCAP) {                              \
                        unsigned* e = ovfe + ((size_t)t * OVFCAP + p2) * 2;   \
                        e[0] = ((unsigned)o_ << 16) | (unsigned)sis;          \
                        e[1] = __float_as_uint(w_);                           \
                    }                                                         \
                }                                                             \
            }
        CLAIM(ty,     tx,     wx0 * wy0)
        CLAIM(ty,     tx + 1, wx1 * wy0)
        CLAIM(ty + 1, tx,     wx0 * wy1)
        CLAIM(ty + 1, tx + 1, wx1 * wy1)
        #undef CLAIM

        // Escape fold: only for this tile's CORE pixels (unique owner).
        if ((unsigned)(xs - X0) < (unsigned)TW &&
            (unsigned)(ys - Y0) < (unsigned)TH) {
            int   cx[4] = { ix0, ix0 + 1, ix0,     ix0 + 1 };
            int   cy[4] = { iy0, iy0,     iy0 + 1, iy0 + 1 };
            float cw[4] = { wx0 * wy0, wx1 * wy0, wx0 * wy1, wx1 * wy1 };
            #pragma unroll
            for (int k = 0; k < 4; ++k) {
                if ((unsigned)cx[k] >= (unsigned)W ||
                    (unsigned)cy[k] >= (unsigned)H) continue;
                int tX0 = cx[k] & ~(TW - 1);
                int tY0 = cy[k] & ~(TH - 1);
                bool inpad = (xs >= tX0 - R) && (xs < tX0 + TW + R) &&
                             (ys >= tY0 - R) && (ys < tY0 + TH + R);
                if (inpad) continue;
                int tt = n * (TGX * TGY) + (tY0 >> 5) * TGX + (tX0 >> 6);
                unsigned pos = atomicAdd(&escc[tt], 1u);
                if (pos < (unsigned)ESCCAP) {
                    unsigned* e = esce + ((size_t)tt * ESCCAP + pos) * 3;
                    e[0] = (unsigned)((cy[k] - tY0) * TW + (cx[k] - tX0));
                    e[1] = (unsigned)p;
                    e[2] = __float_as_uint(cw[k] * wm);
                }
            }
        }
    }
    __syncthreads();

    // Denominator from LDS meta + overflow list (escape weights added in
    // gather). Then coalesced flush of the whole meta block.
    const unsigned on = min(ovfc[t], (unsigned)OVFCAP);
    const unsigned* oe = ovfe + (size_t)t * OVFCAP * 2;
    for (int o = threadIdx.x; o < NOUT; o += NTC) {
        unsigned cn = min(cnt[o], (unsigned)K);
        float d = 0.0f;
        for (unsigned s = 0; s < cn; ++s)
            d += __half2float(__ushort_as_half(
                     (unsigned short)(ml[o * K + (int)s] >> 16)));
        for (unsigned i = 0; i < on; ++i)
            if ((oe[2 * i] >> 16) == (unsigned)o)
                d += __uint_as_float(oe[2 * i + 1]);
        den[(size_t)n * HW + (Y0 + o / TW) * W + X0 + o % TW] = d;
    }

    const uint4* mlv = reinterpret_cast<const uint4*>(ml);
    uint4* mtv = reinterpret_cast<uint4*>(mt);
    for (int i = threadIdx.x; i < NOUT * K / 4; i += NTC)
        mtv[i] = mlv[i];
}

// ---------------------------------------------------------------------------
// Kernel 2: gather + fused normalize — SMALL-BLOCK variant. 512 threads
// (8 waves), 4 outputs/thread, single 30 KB LDS buffer -> 4 independent
// blocks/CU (LDS admits 5, the 32-wave cap admits 4). Half-width barriers;
// a barrier-stalled block leaves 3 others running. (512,4) bound = 128 VGPR
// cap -> no spills (R14's failure was the (512,8)=32-VGPR cap + 32x32-tile
// L2 thrash; both avoided here). Meta via 3 coalesced uint4 per output.
// ---------------------------------------------------------------------------
__global__ __launch_bounds__(NTG, 4) void gather_kernel(
    const float* __restrict__ in, const unsigned* __restrict__ meta,
    const unsigned* __restrict__ ovfc, const unsigned* __restrict__ ovfe,
    const unsigned* __restrict__ escc, const unsigned* __restrict__ esce,
    const float* __restrict__ den, float* __restrict__ out)
{
    __shared__ uint2 val[PS];      // 30720 B -> 4 blocks/CU (wave-capped)

    const int b0 = blockIdx.x;
    const int b  = (b0 & 7) * (GGRID / 8) + (b0 >> 3);   // image per XCD
    const int t     = b >> 1;
    const int split = b & 1;
    const int n  = t / (TGX * TGY);
    const int r  = t % (TGX * TGY);
    const int Y0 = (r / TGX) * TH;
    const int X0 = (r % TGX) * TW;
    const int tid = threadIdx.x;

    const unsigned on = min(ovfc[t], (unsigned)OVFCAP);
    const unsigned en = min(escc[t], (unsigned)ESCCAP);
    const unsigned* oe = ovfe + (size_t)t * OVFCAP * 2;
    const unsigned* ee = esce + (size_t)t * ESCCAP * 3;
    const unsigned* mt = meta + (size_t)t * NOUT * K;

    float inv[OPT];
    int   opix[OPT];
    #pragma unroll
    for (int k = 0; k < OPT; ++k) {
        int o = tid + k * NTG;
        opix[k] = (Y0 + o / TW) * W + X0 + o % TW;
        float d = den[(size_t)n * HW + opix[k]];
        for (unsigned i = 0; i < en; ++i)            // escape weights -> den
            if (ee[3 * i] == (unsigned)o) d += __uint_as_float(ee[3 * i + 2]);
        inv[k] = (d == 0.0f) ? 1.0f : 1.0f / d;
    }

    const float* inb0 = in + ((size_t)n * C + split * CPB * CCHB) * HW;

    for (int cc = 0; cc < CPB; ++cc) {
        const float* inb = inb0 + (size_t)cc * CCHB * HW;
        __syncthreads();                 // previous chunk's readers done
        for (int q = tid; q < PS / 4; q += NTG) {    // 960 quads, 2 iters
            int si0 = q * 4;
            int row = si0 / PW;                      // quads don't straddle rows
            int ys  = Y0 - R + row;
            int xs0 = X0 - R + (si0 - row * PW);     // 4-multiple -> 16B aligned
            bool ok = (unsigned)ys < (unsigned)H && (unsigned)xs0 < (unsigned)W;
            float4 g0 = {0,0,0,0}, g1 = g0, g2 = g0, g3 = g0;
            if (ok) {
                const float* pp = inb + ys * W + xs0;
                g0 = *reinterpret_cast<const float4*>(pp);
                g1 = *reinterpret_cast<const float4*>(pp + HW);
                g2 = *reinterpret_cast<const float4*>(pp + 2 * HW);
                g3 = *reinterpret_cast<const float4*>(pp + 3 * HW);
            }
            int sw = (si0 >> 4) & 15;                // quad shares swizzle bits
            val[(si0    ) ^ sw] = make_uint2(packh2(g0.x, g1.x), packh2(g2.x, g3.x));
            val[(si0 + 1) ^ sw] = make_uint2(packh2(g0.y, g1.y), packh2(g2.y, g3.y));
            val[(si0 + 2) ^ sw] = make_uint2(packh2(g0.z, g1.z), packh2(g2.z, g3.z));
            val[(si0 + 3) ^ sw] = make_uint2(packh2(g0.w, g1.w), packh2(g2.w, g3.w));
        }
        __syncthreads();                 // val staged for all

        #pragma unroll
        for (int k = 0; k < OPT; ++k) {
            const int o = tid + k * NTG;
            const uint4* mo4 = reinterpret_cast<const uint4*>(mt + (size_t)o * K);
            uint4 qa = mo4[0], qb = mo4[1], qc = mo4[2];   // 3 coalesced loads
            unsigned mloc[K] = { qa.x, qa.y, qa.z, qa.w,
                                 qb.x, qb.y, qb.z, qb.w,
                                 qc.x, qc.y, qc.z, qc.w };

            float a0 = 0.0f, a1 = 0.0f, a2 = 0.0f, a3 = 0.0f;
            #pragma unroll
            for (int s = 0; s < K; ++s) {
                unsigned m_ = mloc[s];
                float w  = __half2float(__ushort_as_half((unsigned short)(m_ >> 16)));
                uint2 v = val[m_ & 0xffffu];     // si pre-swizzled at claim
                float2 f0 = unpackh2(v.x), f1 = unpackh2(v.y);
                a0 += w * f0.x;  a1 += w * f0.y;
                a2 += w * f1.x;  a3 += w * f1.y;
            }
            for (unsigned i = 0; i < on; ++i) {          // usually 0-3 entries
                unsigned e0 = oe[2 * i];
                if ((e0 >> 16) == (unsigned)o) {
                    float w  = __uint_as_float(oe[2 * i + 1]);
                    uint2 v = val[e0 & 0xffffu];
                    float2 f0 = unpackh2(v.x), f1 = unpackh2(v.y);
                    a0 += w * f0.x;  a1 += w * f0.y;
                    a2 += w * f1.x;  a3 += w * f1.y;
                }
            }
            for (unsigned i = 0; i < en; ++i) {          // usually 0 entries
                if (ee[3 * i] == (unsigned)o) {
                    float w  = __uint_as_float(ee[3 * i + 2]);
                    int   ps = (int)ee[3 * i + 1];
                    a0 += w * inb[ps];
                    a1 += w * inb[ps + HW];
                    a2 += w * inb[ps + 2 * HW];
                    a3 += w * inb[ps + 3 * HW];
                }
            }
            size_t ob = ((size_t)n * C + (split * CPB + cc) * CCHB) * HW + opix[k];
            out[ob]          = a0 * inv[k];
            out[ob + HW]     = a1 * inv[k];
            out[ob + 2 * HW] = a2 * inv[k];
            out[ob + 3 * HW] = a3 * inv[k];
        }
    }
}

extern "C" void kernel_launch(void* const* d_in, const int* in_sizes, int n_in,
                              void* d_out, int out_size, void* d_ws, size_t ws_size,
                              hipStream_t stream)
{
    const float* tenIn     = (const float*)d_in[0];
    const float* tenFlow   = (const float*)d_in[1];
    const float* tenMetric = (const float*)d_in[2];
    float* out = (float*)d_out;

    unsigned* ws  = (unsigned*)d_ws;
    float*    den = (float*)(ws + WS_DEN);
    unsigned* meta = ws + WS_META;
    unsigned* ovfc = ws + WS_OVFC;
    unsigned* ovfe = ws + WS_OVFE;
    unsigned* escc = ws + WS_ESCC;
    unsigned* esce = ws + WS_ESCE;

    // >64 KiB dynamic LDS needs the attribute raised (idempotent, capture-safe).
    hipFuncSetAttribute(reinterpret_cast<const void*>(claim_kernel),
                        hipFuncAttributeMaxDynamicSharedMemorySize,
                        (int)CLAIM_LDS_BYTES);

    hipMemsetAsync(ovfc, 0, TILES * sizeof(unsigned), stream);
    hipMemsetAsync(escc, 0, TILES * sizeof(unsigned), stream);

    claim_kernel<<<TILES, NTC, CLAIM_LDS_BYTES, stream>>>(
        tenFlow, tenMetric, meta, ovfc, ovfe, escc, esce, den);
    gather_kernel<<<GGRID, NTG, 0, stream>>>(tenIn, meta, ovfc, ovfe,
                                             escc, esce, den, out);
}

// Round 17
// 262.270 us; speedup vs baseline: 2.2425x; 2.2425x over previous
//
#include <hip/hip_runtime.h>
#include <hip/hip_fp16.h>
#include <math.h>

// Problem constants: tenIn [8,64,288,512] fp32, flow [8,2,H,W], metric [8,1,H,W].
constexpr int N  = 8;
constexpr int C  = 64;
constexpr int H  = 288;
constexpr int W  = 512;               // power of 2
constexpr int HW = H * W;             // 147456

// Output tiling (R13/R15-proven): 64x32 tiles. R covers max corner
// displacement for this data; escape path (folded into claim) handles
// anything larger exactly, so R is perf-only.
constexpr int TW = 64, TH = 32, R = 8;
constexpr int PW = TW + 2 * R;        // 80
constexpr int PH = TH + 2 * R;        // 48
constexpr int PS = PW * PH;           // 3840 (fits u16)
constexpr int TGX = W / TW;           // 8
constexpr int TGY = H / TH;           // 9
constexpr int TILES = N * TGX * TGY;  // 576
constexpr int NOUT = TH * TW;         // 2048 outputs per tile
constexpr int K = 12;                 // slots per output (zero-filled if unused)
constexpr int CCHB = 4;               // channels per chunk (4 x f16 = 8B entry)
constexpr int NCHUNK = C / CCHB;      // 16
constexpr int NSPLIT = 2;             // channel-halves across gather blocks
constexpr int CPB = NCHUNK / NSPLIT;  // 8 chunks per gather block
constexpr int OVFCAP = 256;           // per-tile overflow entries (slot > K)
constexpr int ESCCAP = 512;           // per-tile escape entries (|disp| > R)
constexpr int NTC = 512;              // claim threads
constexpr int NTG = 512;              // gather threads (8 waves/block)
constexpr int OPT = NOUT / NTG;       // 4 outputs per gather thread (sequential!)
constexpr int GGRID = TILES * NSPLIT; // 1152 = 8 XCDs * 144

// Claim dynamic LDS: cnt[NOUT] + meta[NOUT*K], all u32.
constexpr size_t CLAIM_LDS_WORDS = (size_t)NOUT * (K + 1);      // 26624
constexpr size_t CLAIM_LDS_BYTES = CLAIM_LDS_WORDS * 4;         // 106496

// Workspace layout (4-byte words). Total ~71 MB.
constexpr size_t WS_DEN  = 0;                                    // N*HW f32
constexpr size_t WS_META = WS_DEN  + (size_t)N * HW;             // TILES*NOUT*K (output-major)
constexpr size_t WS_OVFC = WS_META + (size_t)TILES * NOUT * K;   // TILES
constexpr size_t WS_OVFE = WS_OVFC + TILES;                      // TILES*OVFCAP*2
constexpr size_t WS_ESCC = WS_OVFE + (size_t)TILES * OVFCAP * 2; // TILES
constexpr size_t WS_ESCE = WS_ESCC + TILES;                      // TILES*ESCCAP*3

// Entry-index swizzle for 8B entries (bank pair = e mod 16): XOR low 4 bits
// with bits 4..7 -> bijective within each 16-block (PS % 16 == 0), spreads
// staging writes and random reads across banks. si PRE-swizzled at claim.
__device__ __forceinline__ int swz(int si) { return si ^ ((si >> 4) & 15); }

__device__ __forceinline__ unsigned packh2(float a, float b) {
    __half2 h = __floats2half2_rn(a, b);
    return *reinterpret_cast<unsigned*>(&h);
}
__device__ __forceinline__ float2 unpackh2(unsigned u) {
    __half2 h = *reinterpret_cast<__half2*>(&u);
    return __half22float2(h);
}

// ---------------------------------------------------------------------------
// Kernel 1: per-tile claim, LDS-buffered meta, ESCAPE FOLDED IN (unchanged
// from R15). Slot claims into LDS meta [o][K]; den from LDS; coalesced uint4
// flush. Core pixels append out-of-halo corners to the target tile's escape
// list (device atomics; empty for this data); gather adds them to den.
// ---------------------------------------------------------------------------
__global__ __launch_bounds__(NTC) void claim_kernel(
    const float* __restrict__ flow, const float* __restrict__ metric,
    unsigned* __restrict__ meta,
    unsigned* __restrict__ ovfc, unsigned* __restrict__ ovfe,
    unsigned* __restrict__ escc, unsigned* __restrict__ esce,
    float* __restrict__ den)
{
    extern __shared__ unsigned smem[];
    unsigned* cnt = smem;              // NOUT
    unsigned* ml  = smem + NOUT;       // NOUT*K, output-major [o][K]

    for (int i = threadIdx.x; i < NOUT; i += NTC) cnt[i] = 0;
    for (int i = threadIdx.x; i < NOUT * K; i += NTC) ml[i] = 0u;
    __syncthreads();

    const int t  = blockIdx.x;
    const int n  = t / (TGX * TGY);
    const int r  = t % (TGX * TGY);
    const int Y0 = (r / TGX) * TH;
    const int X0 = (r % TGX) * TW;

    const float* fxp = flow + ((size_t)n * 2) * HW;
    const float* fyp = fxp + HW;
    const float* mp  = metric + (size_t)n * HW;
    unsigned* mt = meta + (size_t)t * NOUT * K;

    for (int si = threadIdx.x; si < PS; si += NTC) {
        int ys = Y0 - R + si / PW;
        int xs = X0 - R + si % PW;
        if ((unsigned)ys >= (unsigned)H || (unsigned)xs >= (unsigned)W) continue;
        int p = ys * W + xs;
        float fx = fxp[p] + (float)xs;
        float fy = fyp[p] + (float)ys;
        if (!(isfinite(fx) && isfinite(fy))) continue;
        float x0f = floorf(fx), y0f = floorf(fy);
        int ix0 = (int)x0f, iy0 = (int)y0f;
        int tx = ix0 - X0;
        int ty = iy0 - Y0;
        float wx1 = fx - x0f, wx0 = x0f + 1.0f - fx;
        float wy1 = fy - y0f, wy0 = y0f + 1.0f - fy;
        float wm  = __expf(mp[p]);
        int sis = swz(si);                  // pre-swizzled LDS entry index

        #define CLAIM(TYv, TXv, Wv)                                           \
            if ((unsigned)(TYv) < (unsigned)TH &&                             \
                (unsigned)(TXv) < (unsigned)TW) {                             \
                float w_ = (Wv) * wm;                                         \
                int   o_ = (TYv) * TW + (TXv);                                \
                unsigned slot = atomicAdd(&cnt[o_], 1u);                      \
                if (slot < (unsigned)K) {                                     \
                    ml[o_ * K + (int)slot] =                                  \
                        ((unsigned)__half_as_ushort(__float2half(w_)) << 16)  \
                        | (unsigned)sis;                                      \
                } else {                                                      \
                    unsigned p2 = atomicAdd(&ovfc[t], 1u);                    \
                    if (p2 < (unsigned)OVFCAP) {                              \
                        unsigned* e = ovfe + ((size_t)t * OVFCAP + p2) * 2;   \
                        e[0] = ((unsigned)o_ << 16) | (unsigned)sis;          \
                        e[1] = __float_as_uint(w_);                           \
                    }                                                         \
                }                                                             \
            }
        CLAIM(ty,     tx,     wx0 * wy0)
        CLAIM(ty,     tx + 1, wx1 * wy0)
        CLAIM(ty + 1, tx,     wx0 * wy1)
        CLAIM(ty + 1, tx + 1, wx1 * wy1)
        #undef CLAIM

        // Escape fold: only for this tile's CORE pixels (unique owner).
        if ((unsigned)(xs - X0) < (unsigned)TW &&
            (unsigned)(ys - Y0) < (unsigned)TH) {
            int   cx[4] = { ix0, ix0 + 1, ix0,     ix0 + 1 };
            int   cy[4] = { iy0, iy0,     iy0 + 1, iy0 + 1 };
            float cw[4] = { wx0 * wy0, wx1 * wy0, wx0 * wy1, wx1 * wy1 };
            #pragma unroll
            for (int k = 0; k < 4; ++k) {
                if ((unsigned)cx[k] >= (unsigned)W ||
                    (unsigned)cy[k] >= (unsigned)H) continue;
                int tX0 = cx[k] & ~(TW - 1);
                int tY0 = cy[k] & ~(TH - 1);
                bool inpad = (xs >= tX0 - R) && (xs < tX0 + TW + R) &&
                             (ys >= tY0 - R) && (ys < tY0 + TH + R);
                if (inpad) continue;
                int tt = n * (TGX * TGY) + (tY0 >> 5) * TGX + (tX0 >> 6);
                unsigned pos = atomicAdd(&escc[tt], 1u);
                if (pos < (unsigned)ESCCAP) {
                    unsigned* e = esce + ((size_t)tt * ESCCAP + pos) * 3;
                    e[0] = (unsigned)((cy[k] - tY0) * TW + (cx[k] - tX0));
                    e[1] = (unsigned)p;
                    e[2] = __float_as_uint(cw[k] * wm);
                }
            }
        }
    }
    __syncthreads();

    // Denominator from LDS meta + overflow list (escape weights added in
    // gather). Then coalesced flush of the whole meta block.
    const unsigned on = min(ovfc[t], (unsigned)OVFCAP);
    const unsigned* oe = ovfe + (size_t)t * OVFCAP * 2;
    for (int o = threadIdx.x; o < NOUT; o += NTC) {
        unsigned cn = min(cnt[o], (unsigned)K);
        float d = 0.0f;
        for (unsigned s = 0; s < cn; ++s)
            d += __half2float(__ushort_as_half(
                     (unsigned short)(ml[o * K + (int)s] >> 16)));
        for (unsigned i = 0; i < on; ++i)
            if ((oe[2 * i] >> 16) == (unsigned)o)
                d += __uint_as_float(oe[2 * i + 1]);
        den[(size_t)n * HW + (Y0 + o / TW) * W + X0 + o % TW] = d;
    }

    const uint4* mlv = reinterpret_cast<const uint4*>(ml);
    uint4* mtv = reinterpret_cast<uint4*>(mt);
    for (int i = threadIdx.x; i < NOUT * K / 4; i += NTC)
        mtv[i] = mlv[i];
}

// ---------------------------------------------------------------------------
// Kernel 2: gather + fused normalize — small-block, SEQUENTIAL-output
// variant. 512 threads (8 waves), 4 outputs/thread processed one at a time
// (#pragma unroll 1: exactly R15's per-output body, one mloc live at a time
// -> fits the 64-VGPR tier with NO spills, unlike R16's 4-way unroll).
// Per-output inverse-den lives in LDS (invs[NOUT]) to avoid runtime-indexed
// register arrays (-> scratch). 38.9 KB LDS -> 4 blocks/CU (wave-capped);
// half-width barriers; 4 independent blocks/CU hide staging latency.
// ---------------------------------------------------------------------------
__global__ __launch_bounds__(NTG, 4) void gather_kernel(
    const float* __restrict__ in, const unsigned* __restrict__ meta,
    const unsigned* __restrict__ ovfc, const unsigned* __restrict__ ovfe,
    const unsigned* __restrict__ escc, const unsigned* __restrict__ esce,
    const float* __restrict__ den, float* __restrict__ out)
{
    __shared__ uint2 val[PS];      // 30720 B
    __shared__ float invs[NOUT];   // 8192 B -> 38912 total, 4 blocks/CU

    const int b0 = blockIdx.x;
    const int b  = (b0 & 7) * (GGRID / 8) + (b0 >> 3);   // image per XCD
    const int t     = b >> 1;
    const int split = b & 1;
    const int n  = t / (TGX * TGY);
    const int r  = t % (TGX * TGY);
    const int Y0 = (r / TGX) * TH;
    const int X0 = (r % TGX) * TW;
    const int tid = threadIdx.x;

    const unsigned on = min(ovfc[t], (unsigned)OVFCAP);
    const unsigned en = min(escc[t], (unsigned)ESCCAP);
    const unsigned* oe = ovfe + (size_t)t * OVFCAP * 2;
    const unsigned* ee = esce + (size_t)t * ESCCAP * 3;
    const unsigned* mt = meta + (size_t)t * NOUT * K;

    // Per-output 1/den into LDS (escape weights folded). Coalesced den reads.
    for (int o = tid; o < NOUT; o += NTG) {
        float d = den[(size_t)n * HW + (Y0 + o / TW) * W + X0 + o % TW];
        for (unsigned i = 0; i < en; ++i)
            if (ee[3 * i] == (unsigned)o) d += __uint_as_float(ee[3 * i + 2]);
        invs[o] = (d == 0.0f) ? 1.0f : 1.0f / d;
    }
    // (visibility covered by the post-staging barrier below)

    const float* inb0 = in + ((size_t)n * C + split * CPB * CCHB) * HW;

    for (int cc = 0; cc < CPB; ++cc) {
        const float* inb = inb0 + (size_t)cc * CCHB * HW;
        if (cc) __syncthreads();         // previous chunk's readers done
        for (int q = tid; q < PS / 4; q += NTG) {    // 960 quads, <=2 iters
            int si0 = q * 4;
            int row = si0 / PW;                      // quads don't straddle rows
            int ys  = Y0 - R + row;
            int xs0 = X0 - R + (si0 - row * PW);     // 4-multiple -> 16B aligned
            bool ok = (unsigned)ys < (unsigned)H && (unsigned)xs0 < (unsigned)W;
            float4 g0 = {0,0,0,0}, g1 = g0, g2 = g0, g3 = g0;
            if (ok) {
                const float* pp = inb + ys * W + xs0;
                g0 = *reinterpret_cast<const float4*>(pp);
                g1 = *reinterpret_cast<const float4*>(pp + HW);
                g2 = *reinterpret_cast<const float4*>(pp + 2 * HW);
                g3 = *reinterpret_cast<const float4*>(pp + 3 * HW);
            }
            int sw = (si0 >> 4) & 15;                // quad shares swizzle bits
            val[(si0    ) ^ sw] = make_uint2(packh2(g0.x, g1.x), packh2(g2.x, g3.x));
            val[(si0 + 1) ^ sw] = make_uint2(packh2(g0.y, g1.y), packh2(g2.y, g3.y));
            val[(si0 + 2) ^ sw] = make_uint2(packh2(g0.z, g1.z), packh2(g2.z, g3.z));
            val[(si0 + 3) ^ sw] = make_uint2(packh2(g0.w, g1.w), packh2(g2.w, g3.w));
        }
        __syncthreads();                 // val (and, at cc==0, invs) staged

        #pragma unroll 1                 // SEQUENTIAL outputs: one mloc live
        for (int kp = 0; kp < OPT; ++kp) {
            const int o = tid + kp * NTG;
            const uint4* mo4 = reinterpret_cast<const uint4*>(mt + (size_t)o * K);
            uint4 qa = mo4[0], qb = mo4[1], qc = mo4[2];   // 3 coalesced loads
            unsigned mloc[K] = { qa.x, qa.y, qa.z, qa.w,
                                 qb.x, qb.y, qb.z, qb.w,
                                 qc.x, qc.y, qc.z, qc.w };

            float a0 = 0.0f, a1 = 0.0f, a2 = 0.0f, a3 = 0.0f;
            #pragma unroll
            for (int s = 0; s < K; ++s) {
                unsigned m_ = mloc[s];
                float w  = __half2float(__ushort_as_half((unsigned short)(m_ >> 16)));
                uint2 v = val[m_ & 0xffffu];     // si pre-swizzled at claim
                float2 f0 = unpackh2(v.x), f1 = unpackh2(v.y);
                a0 += w * f0.x;  a1 += w * f0.y;
                a2 += w * f1.x;  a3 += w * f1.y;
            }
            for (unsigned i = 0; i < on; ++i) {          // usually 0-3 entries
                unsigned e0 = oe[2 * i];
                if ((e0 >> 16) == (unsigned)o) {
                    float w  = __uint_as_float(oe[2 * i + 1]);
                    uint2 v = val[e0 & 0xffffu];
                    float2 f0 = unpackh2(v.x), f1 = unpackh2(v.y);
                    a0 += w * f0.x;  a1 += w * f0.y;
                    a2 += w * f1.x;  a3 += w * f1.y;
                }
            }
            for (unsigned i = 0; i < en; ++i) {          // usually 0 entries
                if (ee[3 * i] == (unsigned)o) {
                    float w  = __uint_as_float(ee[3 * i + 2]);
                    int   ps = (int)ee[3 * i + 1];
                    a0 += w * inb[ps];
                    a1 += w * inb[ps + HW];
                    a2 += w * inb[ps + 2 * HW];
                    a3 += w * inb[ps + 3 * HW];
                }
            }
            float iv  = invs[o];                         // LDS, conflict-free
            int   opx = (Y0 + o / TW) * W + X0 + o % TW;
            size_t ob = ((size_t)n * C + (split * CPB + cc) * CCHB) * HW + opx;
            out[ob]          = a0 * iv;
            out[ob + HW]     = a1 * iv;
            out[ob + 2 * HW] = a2 * iv;
            out[ob + 3 * HW] = a3 * iv;
        }
    }
}

extern "C" void kernel_launch(void* const* d_in, const int* in_sizes, int n_in,
                              void* d_out, int out_size, void* d_ws, size_t ws_size,
                              hipStream_t stream)
{
    const float* tenIn     = (const float*)d_in[0];
    const float* tenFlow   = (const float*)d_in[1];
    const float* tenMetric = (const float*)d_in[2];
    float* out = (float*)d_out;

    unsigned* ws  = (unsigned*)d_ws;
    float*    den = (float*)(ws + WS_DEN);
    unsigned* meta = ws + WS_META;
    unsigned* ovfc = ws + WS_OVFC;
    unsigned* ovfe = ws + WS_OVFE;
    unsigned* escc = ws + WS_ESCC;
    unsigned* esce = ws + WS_ESCE;

    // >64 KiB dynamic LDS needs the attribute raised (idempotent, capture-safe).
    hipFuncSetAttribute(reinterpret_cast<const void*>(claim_kernel),
                        hipFuncAttributeMaxDynamicSharedMemorySize,
                        (int)CLAIM_LDS_BYTES);

    hipMemsetAsync(ovfc, 0, TILES * sizeof(unsigned), stream);
    hipMemsetAsync(escc, 0, TILES * sizeof(unsigned), stream);

    claim_kernel<<<TILES, NTC, CLAIM_LDS_BYTES, stream>>>(
        tenFlow, tenMetric, meta, ovfc, ovfe, escc, esce, den);
    gather_kernel<<<GGRID, NTG, 0, stream>>>(tenIn, meta, ovfc, ovfe,
                                             escc, esce, den, out);
}

// Round 18
// 229.660 us; speedup vs baseline: 2.5609x; 1.1420x over previous
//
#include <hip/hip_runtime.h>
#include <hip/hip_fp16.h>
#include <math.h>

// Problem constants: tenIn [8,64,288,512] fp32, flow [8,2,H,W], metric [8,1,H,W].
constexpr int N  = 8;
constexpr int C  = 64;
constexpr int H  = 288;
constexpr int W  = 512;               // power of 2
constexpr int HW = H * W;             // 147456

// Output tiling (R13/R15-proven): 64x32 tiles. R covers max corner
// displacement for this data; escape path (folded into claim) handles
// anything larger exactly, so R is perf-only.
constexpr int TW = 64, TH = 32, R = 8;
constexpr int PW = TW + 2 * R;        // 80
constexpr int PH = TH + 2 * R;        // 48
constexpr int PS = PW * PH;           // 3840 (fits u16)
constexpr int TGX = W / TW;           // 8
constexpr int TGY = H / TH;           // 9
constexpr int TILES = N * TGX * TGY;  // 576
constexpr int NOUT = TH * TW;         // 2048 outputs per tile
constexpr int K = 12;                 // slots per output (zero-filled if unused)
constexpr int CCHB = 4;               // channels per chunk (4 x f16 = 8B entry)
constexpr int NCHUNK = C / CCHB;      // 16
constexpr int NSPLIT = 2;             // channel-halves across gather blocks
constexpr int CPB = NCHUNK / NSPLIT;  // 8 chunks per gather block
constexpr int OVFCAP = 256;           // per-tile overflow entries (slot > K)
constexpr int ESCCAP = 512;           // per-tile escape entries (|disp| > R)
constexpr int NTC = 512;              // claim threads
constexpr int NTG = 1024;             // gather threads (16 waves/block)
constexpr int GGRID = TILES * NSPLIT; // 1152 = 8 XCDs * 144

// Claim dynamic LDS: cnt[NOUT] + meta[NOUT*K], all u32.
constexpr size_t CLAIM_LDS_WORDS = (size_t)NOUT * (K + 1);      // 26624
constexpr size_t CLAIM_LDS_BYTES = CLAIM_LDS_WORDS * 4;         // 106496

// Workspace layout (4-byte words). Total ~71 MB.
constexpr size_t WS_DEN  = 0;                                    // N*HW f32
constexpr size_t WS_META = WS_DEN  + (size_t)N * HW;             // TILES*NOUT*K (output-major)
constexpr size_t WS_OVFC = WS_META + (size_t)TILES * NOUT * K;   // TILES
constexpr size_t WS_OVFE = WS_OVFC + TILES;                      // TILES*OVFCAP*2
constexpr size_t WS_ESCC = WS_OVFE + (size_t)TILES * OVFCAP * 2; // TILES
constexpr size_t WS_ESCE = WS_ESCC + TILES;                      // TILES*ESCCAP*3

// Entry-index swizzle for 8B entries (bank pair = e mod 16): XOR low 4 bits
// with bits 4..7 -> bijective within each 16-block (PS % 16 == 0), spreads
// staging writes and random reads across banks. si PRE-swizzled at claim.
__device__ __forceinline__ int swz(int si) { return si ^ ((si >> 4) & 15); }

__device__ __forceinline__ unsigned packh2(float a, float b) {
    __half2 h = __floats2half2_rn(a, b);
    return *reinterpret_cast<unsigned*>(&h);
}
__device__ __forceinline__ float2 unpackh2(unsigned u) {
    __half2 h = *reinterpret_cast<__half2*>(&u);
    return __half22float2(h);
}

// ---------------------------------------------------------------------------
// Kernel 1: per-tile claim, LDS-buffered meta, ESCAPE FOLDED IN.
// - slot claims into LDS meta [o][K] (random 4B LDS writes); den from LDS;
//   whole meta block flushed coalesced (uint4) at the end.
// - for CORE pixels (unique owner tile per pixel): any corner whose target
//   tile's halo does NOT contain this source is appended to the TARGET
//   tile's escape list via device atomics (empty for this data). Escape
//   weights are added to den inside gather (no ordering hazard).
// ---------------------------------------------------------------------------
__global__ __launch_bounds__(NTC) void claim_kernel(
    const float* __restrict__ flow, const float* __restrict__ metric,
    unsigned* __restrict__ meta,
    unsigned* __restrict__ ovfc, unsigned* __restrict__ ovfe,
    unsigned* __restrict__ escc, unsigned* __restrict__ esce,
    float* __restrict__ den)
{
    extern __shared__ unsigned smem[];
    unsigned* cnt = smem;              // NOUT
    unsigned* ml  = smem + NOUT;       // NOUT*K, output-major [o][K]

    for (int i = threadIdx.x; i < NOUT; i += NTC) cnt[i] = 0;
    for (int i = threadIdx.x; i < NOUT * K; i += NTC) ml[i] = 0u;
    __syncthreads();

    const int t  = blockIdx.x;
    const int n  = t / (TGX * TGY);
    const int r  = t % (TGX * TGY);
    const int Y0 = (r / TGX) * TH;
    const int X0 = (r % TGX) * TW;

    const float* fxp = flow + ((size_t)n * 2) * HW;
    const float* fyp = fxp + HW;
    const float* mp  = metric + (size_t)n * HW;
    unsigned* mt = meta + (size_t)t * NOUT * K;

    for (int si = threadIdx.x; si < PS; si += NTC) {
        int ys = Y0 - R + si / PW;
        int xs = X0 - R + si % PW;
        if ((unsigned)ys >= (unsigned)H || (unsigned)xs >= (unsigned)W) continue;
        int p = ys * W + xs;
        float fx = fxp[p] + (float)xs;
        float fy = fyp[p] + (float)ys;
        if (!(isfinite(fx) && isfinite(fy))) continue;
        float x0f = floorf(fx), y0f = floorf(fy);
        int ix0 = (int)x0f, iy0 = (int)y0f;
        int tx = ix0 - X0;
        int ty = iy0 - Y0;
        float wx1 = fx - x0f, wx0 = x0f + 1.0f - fx;
        float wy1 = fy - y0f, wy0 = y0f + 1.0f - fy;
        float wm  = __expf(mp[p]);
        int sis = swz(si);                  // pre-swizzled LDS entry index

        #define CLAIM(TYv, TXv, Wv)                                           \
            if ((unsigned)(TYv) < (unsigned)TH &&                             \
                (unsigned)(TXv) < (unsigned)TW) {                             \
                float w_ = (Wv) * wm;                                         \
                int   o_ = (TYv) * TW + (TXv);                                \
                unsigned slot = atomicAdd(&cnt[o_], 1u);                      \
                if (slot < (unsigned)K) {                                     \
                    ml[o_ * K + (int)slot] =                                  \
                        ((unsigned)__half_as_ushort(__float2half(w_)) << 16)  \
                        | (unsigned)sis;                                      \
                } else {                                                      \
                    unsigned p2 = atomicAdd(&ovfc[t], 1u);                    \
                    if (p2 < (unsigned)OVFCAP) {                              \
                        unsigned* e = ovfe + ((size_t)t * OVFCAP + p2) * 2;   \
                        e[0] = ((unsigned)o_ << 16) | (unsigned)sis;          \
                        e[1] = __float_as_uint(w_);                           \
                    }                                                         \
                }                                                             \
            }
        CLAIM(ty,     tx,     wx0 * wy0)
        CLAIM(ty,     tx + 1, wx1 * wy0)
        CLAIM(ty + 1, tx,     wx0 * wy1)
        CLAIM(ty + 1, tx + 1, wx1 * wy1)
        #undef CLAIM

        // Escape fold: only for this tile's CORE pixels (unique owner).
        if ((unsigned)(xs - X0) < (unsigned)TW &&
            (unsigned)(ys - Y0) < (unsigned)TH) {
            int   cx[4] = { ix0, ix0 + 1, ix0,     ix0 + 1 };
            int   cy[4] = { iy0, iy0,     iy0 + 1, iy0 + 1 };
            float cw[4] = { wx0 * wy0, wx1 * wy0, wx0 * wy1, wx1 * wy1 };
            #pragma unroll
            for (int k = 0; k < 4; ++k) {
                if ((unsigned)cx[k] >= (unsigned)W ||
                    (unsigned)cy[k] >= (unsigned)H) continue;
                int tX0 = cx[k] & ~(TW - 1);
                int tY0 = cy[k] & ~(TH - 1);
                bool inpad = (xs >= tX0 - R) && (xs < tX0 + TW + R) &&
                             (ys >= tY0 - R) && (ys < tY0 + TH + R);
                if (inpad) continue;
                int tt = n * (TGX * TGY) + (tY0 >> 5) * TGX + (tX0 >> 6);
                unsigned pos = atomicAdd(&escc[tt], 1u);
                if (pos < (unsigned)ESCCAP) {
                    unsigned* e = esce + ((size_t)tt * ESCCAP + pos) * 3;
                    e[0] = (unsigned)((cy[k] - tY0) * TW + (cx[k] - tX0));
                    e[1] = (unsigned)p;
                    e[2] = __float_as_uint(cw[k] * wm);
                }
            }
        }
    }
    __syncthreads();

    // Denominator from LDS meta + overflow list (escape weights added in
    // gather). Then coalesced flush of the whole meta block.
    const unsigned on = min(ovfc[t], (unsigned)OVFCAP);
    const unsigned* oe = ovfe + (size_t)t * OVFCAP * 2;
    for (int o = threadIdx.x; o < NOUT; o += NTC) {
        unsigned cn = min(cnt[o], (unsigned)K);
        float d = 0.0f;
        for (unsigned s = 0; s < cn; ++s)
            d += __half2float(__ushort_as_half(
                     (unsigned short)(ml[o * K + (int)s] >> 16)));
        for (unsigned i = 0; i < on; ++i)
            if ((oe[2 * i] >> 16) == (unsigned)o)
                d += __uint_as_float(oe[2 * i + 1]);
        den[(size_t)n * HW + (Y0 + o / TW) * W + X0 + o % TW] = d;
    }

    const uint4* mlv = reinterpret_cast<const uint4*>(ml);
    uint4* mtv = reinterpret_cast<uint4*>(mt);
    for (int i = threadIdx.x; i < NOUT * K / 4; i += NTC)
        mtv[i] = mlv[i];
}

// ---------------------------------------------------------------------------
// Kernel 2: gather + fused normalize (R15-proven config — empirical optimum).
// Block = (tile t, channel-half split), XCD-swizzled (one image per XCD).
// LDS entry = 8B of 4 f16 channels; random gathers are ds_read_b64;
// double-buffered staging with register prefetch (one barrier/chunk);
// 3 coalesced uint4 meta loads; __launch_bounds__(1024,4) -> 64 VGPR,
// no spills. 61 KB LDS -> 2 blocks/CU: keeps the per-XCD L2 working set
// (meta + halo planes) inside 4 MB — R17 proved 4 blocks/CU thrashes L2
// (FETCH 225->456 MB) and loses more than the occupancy gain.
// ---------------------------------------------------------------------------
__global__ __launch_bounds__(NTG, 4) void gather_kernel(
    const float* __restrict__ in, const unsigned* __restrict__ meta,
    const unsigned* __restrict__ ovfc, const unsigned* __restrict__ ovfe,
    const unsigned* __restrict__ escc, const unsigned* __restrict__ esce,
    const float* __restrict__ den, float* __restrict__ out)
{
    __shared__ uint2 val[2][PS];   // 61440 B total

    const int b0 = blockIdx.x;
    const int b  = (b0 & 7) * (GGRID / 8) + (b0 >> 3);
    const int t     = b >> 1;
    const int split = b & 1;
    const int n  = t / (TGX * TGY);
    const int r  = t % (TGX * TGY);
    const int Y0 = (r / TGX) * TH;
    const int X0 = (r % TGX) * TW;

    const unsigned on = min(ovfc[t], (unsigned)OVFCAP);
    const unsigned en = min(escc[t], (unsigned)ESCCAP);
    const unsigned* oe = ovfe + (size_t)t * OVFCAP * 2;
    const unsigned* ee = esce + (size_t)t * ESCCAP * 3;
    const unsigned* mt = meta + (size_t)t * NOUT * K;

    float inv[2];
    int   opix[2];
    #pragma unroll
    for (int k = 0; k < 2; ++k) {
        int o = threadIdx.x + k * NTG;
        opix[k] = (Y0 + o / TW) * W + X0 + o % TW;
        float d = den[(size_t)n * HW + opix[k]];
        for (unsigned i = 0; i < en; ++i)            // escape weights -> den
            if (ee[3 * i] == (unsigned)o) d += __uint_as_float(ee[3 * i + 2]);
        inv[k] = (d == 0.0f) ? 1.0f : 1.0f / d;
    }

    // Per-thread staging geometry (fixed across chunks).
    const bool stager = threadIdx.x < PS / 4;    // 960 staging threads
    int si0 = 0, sw = 0, soff = 0;
    bool ok = false;
    if (stager) {
        si0 = threadIdx.x * 4;
        int row = si0 / PW;                      // quads never straddle rows
        int ys  = Y0 - R + row;
        int xs0 = X0 - R + (si0 - row * PW);
        ok  = (unsigned)ys < (unsigned)H && (unsigned)xs0 < (unsigned)W;
        sw  = (si0 >> 4) & 15;
        soff = ys * W + xs0;
    }
    const float* inb0 = in + ((size_t)n * C + split * CPB * CCHB) * HW;

    float4 g0 = {0,0,0,0}, g1 = g0, g2 = g0, g3 = g0;
    if (stager && ok) {
        const float* pp = inb0 + soff;
        g0 = *reinterpret_cast<const float4*>(pp);
        g1 = *reinterpret_cast<const float4*>(pp + HW);
        g2 = *reinterpret_cast<const float4*>(pp + 2 * HW);
        g3 = *reinterpret_cast<const float4*>(pp + 3 * HW);
    }
    if (stager) {
        val[0][(si0    ) ^ sw] = make_uint2(packh2(g0.x, g1.x), packh2(g2.x, g3.x));
        val[0][(si0 + 1) ^ sw] = make_uint2(packh2(g0.y, g1.y), packh2(g2.y, g3.y));
        val[0][(si0 + 2) ^ sw] = make_uint2(packh2(g0.z, g1.z), packh2(g2.z, g3.z));
        val[0][(si0 + 3) ^ sw] = make_uint2(packh2(g0.w, g1.w), packh2(g2.w, g3.w));
    }

    int cur = 0;
    for (int cc = 0; cc < CPB; ++cc) {
        __syncthreads();                          // val[cur] ready for all
        const float* inb = inb0 + (size_t)cc * CCHB * HW;

        // Prefetch next chunk's planes (latency hidden under compute below).
        if (cc + 1 < CPB && stager) {
            g0 = make_float4(0,0,0,0); g1 = g0; g2 = g0; g3 = g0;
            if (ok) {
                const float* pn = inb + (size_t)CCHB * HW + soff;
                g0 = *reinterpret_cast<const float4*>(pn);
                g1 = *reinterpret_cast<const float4*>(pn + HW);
                g2 = *reinterpret_cast<const float4*>(pn + 2 * HW);
                g3 = *reinterpret_cast<const float4*>(pn + 3 * HW);
            }
        }

        const uint2* vb = val[cur];
        #pragma unroll
        for (int k = 0; k < 2; ++k) {
            const int o = threadIdx.x + k * NTG;
            const uint4* mo4 = reinterpret_cast<const uint4*>(mt + (size_t)o * K);
            uint4 qa = mo4[0], qb = mo4[1], qc = mo4[2];   // 3 coalesced loads
            unsigned mloc[K] = { qa.x, qa.y, qa.z, qa.w,
                                 qb.x, qb.y, qb.z, qb.w,
                                 qc.x, qc.y, qc.z, qc.w };

            float a0 = 0.0f, a1 = 0.0f, a2 = 0.0f, a3 = 0.0f;
            #pragma unroll
            for (int s = 0; s < K; ++s) {
                unsigned m_ = mloc[s];
                float w  = __half2float(__ushort_as_half((unsigned short)(m_ >> 16)));
                uint2 v = vb[m_ & 0xffffu];       // si pre-swizzled at claim
                float2 f0 = unpackh2(v.x), f1 = unpackh2(v.y);
                a0 += w * f0.x;  a1 += w * f0.y;
                a2 += w * f1.x;  a3 += w * f1.y;
            }
            for (unsigned i = 0; i < on; ++i) {           // usually 0-3 entries
                unsigned e0 = oe[2 * i];
                if ((e0 >> 16) == (unsigned)o) {
                    float w  = __uint_as_float(oe[2 * i + 1]);
                    uint2 v = vb[e0 & 0xffffu];
                    float2 f0 = unpackh2(v.x), f1 = unpackh2(v.y);
                    a0 += w * f0.x;  a1 += w * f0.y;
                    a2 += w * f1.x;  a3 += w * f1.y;
                }
            }
            for (unsigned i = 0; i < en; ++i) {           // usually 0 entries
                if (ee[3 * i] == (unsigned)o) {
                    float w  = __uint_as_float(ee[3 * i + 2]);
                    int   ps = (int)ee[3 * i + 1];
                    a0 += w * inb[ps];
                    a1 += w * inb[ps + HW];
                    a2 += w * inb[ps + 2 * HW];
                    a3 += w * inb[ps + 3 * HW];
                }
            }
            size_t ob = ((size_t)n * C + (split * CPB + cc) * CCHB) * HW + opix[k];
            out[ob]          = a0 * inv[k];
            out[ob + HW]     = a1 * inv[k];
            out[ob + 2 * HW] = a2 * inv[k];
            out[ob + 3 * HW] = a3 * inv[k];
        }

        // Write the prefetched planes into the other buffer.
        if (cc + 1 < CPB && stager) {
            uint2* vn = val[cur ^ 1];
            vn[(si0    ) ^ sw] = make_uint2(packh2(g0.x, g1.x), packh2(g2.x, g3.x));
            vn[(si0 + 1) ^ sw] = make_uint2(packh2(g0.y, g1.y), packh2(g2.y, g3.y));
            vn[(si0 + 2) ^ sw] = make_uint2(packh2(g0.z, g1.z), packh2(g2.z, g3.z));
            vn[(si0 + 3) ^ sw] = make_uint2(packh2(g0.w, g1.w), packh2(g2.w, g3.w));
        }
        cur ^= 1;
    }
}

extern "C" void kernel_launch(void* const* d_in, const int* in_sizes, int n_in,
                              void* d_out, int out_size, void* d_ws, size_t ws_size,
                              hipStream_t stream)
{
    const float* tenIn     = (const float*)d_in[0];
    const float* tenFlow   = (const float*)d_in[1];
    const float* tenMetric = (const float*)d_in[2];
    float* out = (float*)d_out;

    unsigned* ws  = (unsigned*)d_ws;
    float*    den = (float*)(ws + WS_DEN);
    unsigned* meta = ws + WS_META;
    unsigned* ovfc = ws + WS_OVFC;
    unsigned* ovfe = ws + WS_OVFE;
    unsigned* escc = ws + WS_ESCC;
    unsigned* esce = ws + WS_ESCE;

    // >64 KiB dynamic LDS needs the attribute raised (idempotent, capture-safe).
    hipFuncSetAttribute(reinterpret_cast<const void*>(claim_kernel),
                        hipFuncAttributeMaxDynamicSharedMemorySize,
                        (int)CLAIM_LDS_BYTES);

    hipMemsetAsync(ovfc, 0, TILES * sizeof(unsigned), stream);
    hipMemsetAsync(escc, 0, TILES * sizeof(unsigned), stream);

    claim_kernel<<<TILES, NTC, CLAIM_LDS_BYTES, stream>>>(
        tenFlow, tenMetric, meta, ovfc, ovfe, escc, esce, den);
    gather_kernel<<<GGRID, NTG, 0, stream>>>(tenIn, meta, ovfc, ovfe,
                                             escc, esce, den, out);
}